// Round 1
// baseline (134.777 us; speedup 1.0000x reference)
//
#include <hip/hip_runtime.h>
#include <math.h>

#define BB 32
#define SS 2048
#define DD 1024
#define CHUNKS 32                       // chunks per batch
#define ROWS_PER_CHUNK (SS / CHUNKS)    // 64
#define NWAVES 4
#define ROWS_PER_WAVE (ROWS_PER_CHUNK / NWAVES)  // 16
#define PSTRIDE (DD + 4)                // partial stride (16B aligned)

// ---------------- K1: v[b,d] = sum_e st[b,e] * W[e,d] ----------------
__global__ __launch_bounds__(256) void k_v(const float* __restrict__ st,
                                           const float* __restrict__ W,
                                           float* __restrict__ v) {
    const int b = blockIdx.y;
    const int d = blockIdx.x * 256 + threadIdx.x;
    __shared__ float s_st[DD];
    for (int e = threadIdx.x; e < DD; e += 256) s_st[e] = st[b * DD + e];
    __syncthreads();
    float acc = 0.f;
#pragma unroll 8
    for (int e = 0; e < DD; ++e) acc += s_st[e] * W[(size_t)e * DD + d];
    v[b * DD + d] = acc;
}

// ---------------- K2: c[b] = dot(bias, st[b]) ----------------
__global__ __launch_bounds__(256) void k_c(const float* __restrict__ st,
                                           const float* __restrict__ bias,
                                           float* __restrict__ c) {
    const int b = blockIdx.x;
    float acc = 0.f;
    for (int e = threadIdx.x; e < DD; e += 256) acc += st[b * DD + e] * bias[e];
#pragma unroll
    for (int o = 32; o; o >>= 1) acc += __shfl_down(acc, o, 64);
    __shared__ float s[NWAVES];
    if ((threadIdx.x & 63) == 0) s[threadIdx.x >> 6] = acc;
    __syncthreads();
    if (threadIdx.x == 0) c[b] = s[0] + s[1] + s[2] + s[3];
}

// ---------------- K3: main single pass over hx (online softmax) ----------------
__global__ __launch_bounds__(256) void k_main(const float* __restrict__ hx,
                                              const float* __restrict__ mask,
                                              const float* __restrict__ v,
                                              const float* __restrict__ c,
                                              float* __restrict__ part) {
    const int chunk = blockIdx.x;
    const int b = blockIdx.y;
    const int tid = threadIdx.x;
    const int wave = tid >> 6;
    const int lane = tid & 63;

    // v fragment: lane l owns cols 256*k + 4*l .. +3
    float4 vr[4];
    const float* vb = v + b * DD;
#pragma unroll
    for (int k = 0; k < 4; ++k)
        vr[k] = *reinterpret_cast<const float4*>(vb + k * 256 + 4 * lane);

    const float cb = c[b];
    const int s0 = chunk * ROWS_PER_CHUNK + wave * ROWS_PER_WAVE;
    const float* hxb = hx + (size_t)b * SS * DD;
    const float* mb = mask + (size_t)b * SS;

    float m = -INFINITY, l = 0.f;
    float4 u[4];
#pragma unroll
    for (int k = 0; k < 4; ++k) u[k] = make_float4(0.f, 0.f, 0.f, 0.f);

    for (int r = 0; r < ROWS_PER_WAVE; ++r) {
        const int s = s0 + r;
        const float* row = hxb + (size_t)s * DD;
        float4 h[4];
#pragma unroll
        for (int k = 0; k < 4; ++k)
            h[k] = *reinterpret_cast<const float4*>(row + k * 256 + 4 * lane);
        float dot = 0.f;
#pragma unroll
        for (int k = 0; k < 4; ++k)
            dot += h[k].x * vr[k].x + h[k].y * vr[k].y + h[k].z * vr[k].z + h[k].w * vr[k].w;
#pragma unroll
        for (int o = 32; o; o >>= 1) dot += __shfl_xor(dot, o, 64);

        float score = dot + cb;
        const float mk = mb[s];
        score *= mk + (1.0f - mk) * 1e-18f;   // faithful multiplicative mask

        const float nm = fmaxf(m, score);
        const float sc = expf(m - nm);        // 0 when m == -inf
        const float p = expf(score - nm);
        l = l * sc + p;
#pragma unroll
        for (int k = 0; k < 4; ++k) {
            u[k].x = u[k].x * sc + p * h[k].x;
            u[k].y = u[k].y * sc + p * h[k].y;
            u[k].z = u[k].z * sc + p * h[k].z;
            u[k].w = u[k].w * sc + p * h[k].w;
        }
        m = nm;
    }

    // combine 4 waves in LDS
    __shared__ float s_m[NWAVES], s_l[NWAVES];
    __shared__ float s_u[NWAVES][DD];   // 16 KB
    if (lane == 0) { s_m[wave] = m; s_l[wave] = l; }
#pragma unroll
    for (int k = 0; k < 4; ++k)
        *reinterpret_cast<float4*>(&s_u[wave][k * 256 + 4 * lane]) = u[k];
    __syncthreads();

    const float M = fmaxf(fmaxf(s_m[0], s_m[1]), fmaxf(s_m[2], s_m[3]));
    const float f0 = expf(s_m[0] - M), f1 = expf(s_m[1] - M);
    const float f2 = expf(s_m[2] - M), f3 = expf(s_m[3] - M);
    const float L = s_l[0] * f0 + s_l[1] * f1 + s_l[2] * f2 + s_l[3] * f3;

    float* pb = part + (size_t)(b * CHUNKS + chunk) * PSTRIDE;
    float4 a0 = *reinterpret_cast<const float4*>(&s_u[0][4 * tid]);
    float4 a1 = *reinterpret_cast<const float4*>(&s_u[1][4 * tid]);
    float4 a2 = *reinterpret_cast<const float4*>(&s_u[2][4 * tid]);
    float4 a3 = *reinterpret_cast<const float4*>(&s_u[3][4 * tid]);
    float4 acc;
    acc.x = a0.x * f0 + a1.x * f1 + a2.x * f2 + a3.x * f3;
    acc.y = a0.y * f0 + a1.y * f1 + a2.y * f2 + a3.y * f3;
    acc.z = a0.z * f0 + a1.z * f1 + a2.z * f2 + a3.z * f3;
    acc.w = a0.w * f0 + a1.w * f1 + a2.w * f2 + a3.w * f3;
    *reinterpret_cast<float4*>(pb + 4 * tid) = acc;
    if (tid == 0) { pb[DD] = M; pb[DD + 1] = L; }
}

// ---------------- K4: combine chunks -> ubar[b,d] = u_total/L ----------------
__global__ __launch_bounds__(256) void k_reduce(const float* __restrict__ part,
                                                float* __restrict__ ubar) {
    const int b = blockIdx.x;
    const int tid = threadIdx.x;
    __shared__ float s_f[CHUNKS];
    __shared__ float s_red[2];
    const float* pb = part + (size_t)b * CHUNKS * PSTRIDE;

    float mi = (tid < CHUNKS) ? pb[tid * PSTRIDE + DD] : -INFINITY;
    float M = mi;
#pragma unroll
    for (int o = 32; o; o >>= 1) M = fmaxf(M, __shfl_xor(M, o, 64));
    if (tid == 0) s_red[0] = M;
    __syncthreads();
    M = s_red[0];

    const float li = (tid < CHUNKS) ? pb[tid * PSTRIDE + DD + 1] : 0.f;
    const float fi = (tid < CHUNKS) ? expf(mi - M) : 0.f;
    if (tid < CHUNKS) s_f[tid] = fi;
    float Lp = li * fi;
#pragma unroll
    for (int o = 32; o; o >>= 1) Lp += __shfl_xor(Lp, o, 64);
    if (tid == 0) s_red[1] = Lp;
    __syncthreads();
    const float invL = 1.f / s_red[1];

    float4 acc = make_float4(0.f, 0.f, 0.f, 0.f);
    for (int i = 0; i < CHUNKS; ++i) {
        const float f = s_f[i];
        float4 ui = *reinterpret_cast<const float4*>(pb + (size_t)i * PSTRIDE + 4 * tid);
        acc.x += f * ui.x; acc.y += f * ui.y; acc.z += f * ui.z; acc.w += f * ui.w;
    }
    acc.x *= invL; acc.y *= invL; acc.z *= invL; acc.w *= invL;
    *reinterpret_cast<float4*>(ubar + (size_t)b * DD + 4 * tid) = acc;
}

// ---------------- K5: ct[b,e] = sum_d ubar[b,d]*W[e,d] + bias[e] ----------------
__global__ __launch_bounds__(256) void k_out(const float* __restrict__ ubar,
                                             const float* __restrict__ W,
                                             const float* __restrict__ bias,
                                             float* __restrict__ out) {
    const int b = blockIdx.y;
    const int e = blockIdx.x * 256 + threadIdx.x;
    __shared__ float s_u[DD];
    for (int d = threadIdx.x; d < DD; d += 256) s_u[d] = ubar[b * DD + d];
    __syncthreads();
    float acc = 0.f;
    const float* wr = W + (size_t)e * DD;
#pragma unroll 4
    for (int d = 0; d < DD; d += 4) {
        float4 w4 = *reinterpret_cast<const float4*>(wr + d);
        acc += s_u[d] * w4.x + s_u[d + 1] * w4.y + s_u[d + 2] * w4.z + s_u[d + 3] * w4.w;
    }
    out[b * DD + e] = acc + bias[e];
}

extern "C" void kernel_launch(void* const* d_in, const int* in_sizes, int n_in,
                              void* d_out, int out_size, void* d_ws, size_t ws_size,
                              hipStream_t stream) {
    const float* st   = (const float*)d_in[0];   // [B,D]
    const float* hx   = (const float*)d_in[1];   // [B,S,D]
    const float* msk  = (const float*)d_in[2];   // [B,S]
    const float* W    = (const float*)d_in[3];   // [D,D]
    const float* bias = (const float*)d_in[4];   // [D]
    float* out = (float*)d_out;                  // [B,D]

    float* ws = (float*)d_ws;
    float* v    = ws;                              // B*D
    float* c    = v + BB * DD;                     // B
    float* part = c + BB;                          // B*CHUNKS*PSTRIDE (base 16B-aligned)
    float* ubar = part + (size_t)BB * CHUNKS * PSTRIDE;  // B*D

    k_v<<<dim3(DD / 256, BB), 256, 0, stream>>>(st, W, v);
    k_c<<<BB, 256, 0, stream>>>(st, bias, c);
    k_main<<<dim3(CHUNKS, BB), 256, 0, stream>>>(hx, msk, v, c, part);
    k_reduce<<<BB, 256, 0, stream>>>(part, ubar);
    k_out<<<dim3(DD / 256, BB), 256, 0, stream>>>(ubar, W, bias, out);
}

// Round 2
// 81.714 us; speedup vs baseline: 1.6494x; 1.6494x over previous
//
#include <hip/hip_runtime.h>
#include <math.h>

#define BB 32
#define SS 2048
#define DD 1024
#define CHUNKS 32                        // chunks per batch (k_main grid.x)
#define ROWS_PER_CHUNK (SS / CHUNKS)     // 64
#define NWAVES 4
#define ROWS_PER_WAVE (ROWS_PER_CHUNK / NWAVES)  // 16
#define PSTRIDE (DD + 4)                 // partial stride (16B aligned)

// k_v split
#define ESPL 8
#define EPB (DD / ESPL)                  // 128 e per block
#define VBG 4                            // b-group blocks
#define VBPG (BB / VBG)                  // 8 b per block

// ---------------- K1: part_v[es][b][d] = sum_{e in es-range} st[b,e]*W[e,d] ----------------
__global__ __launch_bounds__(256) void k_v(const float* __restrict__ st,
                                           const float* __restrict__ W,
                                           float* __restrict__ part_v) {
    const int dchunk = blockIdx.x;       // 0..3
    const int es = blockIdx.y;           // 0..7
    const int bg = blockIdx.z;           // 0..3
    const int tid = threadIdx.x;
    const int d = dchunk * 256 + tid;
    const int e0 = es * EPB;
    const int b0 = bg * VBPG;

    __shared__ float st_s[VBPG][EPB];    // 4 KB
    for (int i = tid; i < VBPG * EPB; i += 256)
        st_s[i >> 7][i & 127] = st[(b0 + (i >> 7)) * DD + e0 + (i & 127)];
    __syncthreads();

    float acc[VBPG];
#pragma unroll
    for (int j = 0; j < VBPG; ++j) acc[j] = 0.f;

    for (int e = 0; e < EPB; ++e) {
        const float w = W[(size_t)(e0 + e) * DD + d];
#pragma unroll
        for (int j = 0; j < VBPG; ++j) acc[j] += st_s[j][e] * w;
    }
#pragma unroll
    for (int j = 0; j < VBPG; ++j)
        part_v[((size_t)es * BB + b0 + j) * DD + d] = acc[j];
}

// ---------------- K2: main single pass over hx (online softmax, groups of 4 rows) ----------------
__global__ __launch_bounds__(256) void k_main(const float* __restrict__ hx,
                                              const float* __restrict__ mask,
                                              const float* __restrict__ part_v,
                                              const float* __restrict__ st,
                                              const float* __restrict__ bias,
                                              float* __restrict__ part) {
    const int chunk = blockIdx.x;
    const int b = blockIdx.y;
    const int tid = threadIdx.x;
    const int wave = tid >> 6;
    const int lane = tid & 63;

    // v fragment (lane l owns cols 256k+4l..+3), reduced over the 8 e-splits
    float4 vr[4];
#pragma unroll
    for (int k = 0; k < 4; ++k) vr[k] = make_float4(0.f, 0.f, 0.f, 0.f);
#pragma unroll
    for (int es = 0; es < ESPL; ++es) {
        const float* pv = part_v + ((size_t)es * BB + b) * DD;
#pragma unroll
        for (int k = 0; k < 4; ++k) {
            float4 t = *reinterpret_cast<const float4*>(pv + k * 256 + 4 * lane);
            vr[k].x += t.x; vr[k].y += t.y; vr[k].z += t.z; vr[k].w += t.w;
        }
    }

    // cb = dot(bias, st[b]) computed redundantly per wave (L2-hot reads)
    float cb = 0.f;
    {
        const float* stb = st + b * DD;
#pragma unroll
        for (int k = 0; k < 4; ++k) {
            float4 bv = *reinterpret_cast<const float4*>(bias + k * 256 + 4 * lane);
            float4 sv = *reinterpret_cast<const float4*>(stb + k * 256 + 4 * lane);
            cb += bv.x * sv.x + bv.y * sv.y + bv.z * sv.z + bv.w * sv.w;
        }
#pragma unroll
        for (int o = 32; o; o >>= 1) cb += __shfl_xor(cb, o, 64);
    }

    const int s0 = chunk * ROWS_PER_CHUNK + wave * ROWS_PER_WAVE;
    const float* hxb = hx + (size_t)b * SS * DD;
    const float* mb = mask + (size_t)b * SS;

    float m = -INFINITY, l = 0.f;
    float4 u[4];
#pragma unroll
    for (int k = 0; k < 4; ++k) u[k] = make_float4(0.f, 0.f, 0.f, 0.f);

    for (int g = 0; g < ROWS_PER_WAVE / 4; ++g) {
        const int s = s0 + 4 * g;
        const float* row = hxb + (size_t)s * DD;
        float4 h[4][4];
#pragma unroll
        for (int r = 0; r < 4; ++r)
#pragma unroll
            for (int k = 0; k < 4; ++k)
                h[r][k] = *reinterpret_cast<const float4*>(row + (size_t)r * DD + k * 256 + 4 * lane);

        float d0 = 0.f, d1 = 0.f, d2 = 0.f, d3 = 0.f;
#pragma unroll
        for (int k = 0; k < 4; ++k) {
            d0 += h[0][k].x * vr[k].x + h[0][k].y * vr[k].y + h[0][k].z * vr[k].z + h[0][k].w * vr[k].w;
            d1 += h[1][k].x * vr[k].x + h[1][k].y * vr[k].y + h[1][k].z * vr[k].z + h[1][k].w * vr[k].w;
            d2 += h[2][k].x * vr[k].x + h[2][k].y * vr[k].y + h[2][k].z * vr[k].z + h[2][k].w * vr[k].w;
            d3 += h[3][k].x * vr[k].x + h[3][k].y * vr[k].y + h[3][k].z * vr[k].z + h[3][k].w * vr[k].w;
        }
#pragma unroll
        for (int o = 32; o; o >>= 1) {
            d0 += __shfl_xor(d0, o, 64);
            d1 += __shfl_xor(d1, o, 64);
            d2 += __shfl_xor(d2, o, 64);
            d3 += __shfl_xor(d3, o, 64);
        }

        const float4 mk = *reinterpret_cast<const float4*>(mb + s);
        float sc0 = (d0 + cb) * (mk.x + (1.0f - mk.x) * 1e-18f);
        float sc1 = (d1 + cb) * (mk.y + (1.0f - mk.y) * 1e-18f);
        float sc2 = (d2 + cb) * (mk.z + (1.0f - mk.z) * 1e-18f);
        float sc3 = (d3 + cb) * (mk.w + (1.0f - mk.w) * 1e-18f);

        const float gm = fmaxf(fmaxf(sc0, sc1), fmaxf(sc2, sc3));
        if (gm > m) {                       // wave-uniform branch (post-reduce values)
            const float f = __expf(m - gm); // 0 on first group (m = -inf)
            l *= f;
#pragma unroll
            for (int k = 0; k < 4; ++k) {
                u[k].x *= f; u[k].y *= f; u[k].z *= f; u[k].w *= f;
            }
            m = gm;
        }
        const float p0 = __expf(sc0 - m);
        const float p1 = __expf(sc1 - m);
        const float p2 = __expf(sc2 - m);
        const float p3 = __expf(sc3 - m);
        l += p0 + p1 + p2 + p3;
#pragma unroll
        for (int k = 0; k < 4; ++k) {
            u[k].x += p0 * h[0][k].x + p1 * h[1][k].x + p2 * h[2][k].x + p3 * h[3][k].x;
            u[k].y += p0 * h[0][k].y + p1 * h[1][k].y + p2 * h[2][k].y + p3 * h[3][k].y;
            u[k].z += p0 * h[0][k].z + p1 * h[1][k].z + p2 * h[2][k].z + p3 * h[3][k].z;
            u[k].w += p0 * h[0][k].w + p1 * h[1][k].w + p2 * h[2][k].w + p3 * h[3][k].w;
        }
    }

    // combine 4 waves in LDS
    __shared__ float s_m[NWAVES], s_l[NWAVES];
    __shared__ float s_u[NWAVES][DD];   // 16 KB
    if (lane == 0) { s_m[wave] = m; s_l[wave] = l; }
#pragma unroll
    for (int k = 0; k < 4; ++k)
        *reinterpret_cast<float4*>(&s_u[wave][k * 256 + 4 * lane]) = u[k];
    __syncthreads();

    const float M = fmaxf(fmaxf(s_m[0], s_m[1]), fmaxf(s_m[2], s_m[3]));
    const float f0 = __expf(s_m[0] - M), f1 = __expf(s_m[1] - M);
    const float f2 = __expf(s_m[2] - M), f3 = __expf(s_m[3] - M);
    const float L = s_l[0] * f0 + s_l[1] * f1 + s_l[2] * f2 + s_l[3] * f3;

    float* pb = part + (size_t)(b * CHUNKS + chunk) * PSTRIDE;
    float4 a0 = *reinterpret_cast<const float4*>(&s_u[0][4 * tid]);
    float4 a1 = *reinterpret_cast<const float4*>(&s_u[1][4 * tid]);
    float4 a2 = *reinterpret_cast<const float4*>(&s_u[2][4 * tid]);
    float4 a3 = *reinterpret_cast<const float4*>(&s_u[3][4 * tid]);
    float4 acc;
    acc.x = a0.x * f0 + a1.x * f1 + a2.x * f2 + a3.x * f3;
    acc.y = a0.y * f0 + a1.y * f1 + a2.y * f2 + a3.y * f3;
    acc.z = a0.z * f0 + a1.z * f1 + a2.z * f2 + a3.z * f3;
    acc.w = a0.w * f0 + a1.w * f1 + a2.w * f2 + a3.w * f3;
    *reinterpret_cast<float4*>(pb + 4 * tid) = acc;
    if (tid == 0) { pb[DD] = M; pb[DD + 1] = L; }
}

// ---------------- K3: combine chunks -> ubar[b,d] = u_total/L ----------------
__global__ __launch_bounds__(256) void k_reduce(const float* __restrict__ part,
                                                float* __restrict__ ubar) {
    const int b = blockIdx.x;
    const int tid = threadIdx.x;
    __shared__ float s_f[CHUNKS];
    __shared__ float s_red[2];
    const float* pb = part + (size_t)b * CHUNKS * PSTRIDE;

    float mi = (tid < CHUNKS) ? pb[tid * PSTRIDE + DD] : -INFINITY;
    float M = mi;
#pragma unroll
    for (int o = 32; o; o >>= 1) M = fmaxf(M, __shfl_xor(M, o, 64));
    if (tid == 0) s_red[0] = M;
    __syncthreads();
    M = s_red[0];

    const float li = (tid < CHUNKS) ? pb[tid * PSTRIDE + DD + 1] : 0.f;
    const float fi = (tid < CHUNKS) ? __expf(mi - M) : 0.f;
    if (tid < CHUNKS) s_f[tid] = fi;
    float Lp = li * fi;
#pragma unroll
    for (int o = 32; o; o >>= 1) Lp += __shfl_xor(Lp, o, 64);
    if (tid == 0) s_red[1] = Lp;
    __syncthreads();
    const float invL = 1.f / s_red[1];

    float4 acc = make_float4(0.f, 0.f, 0.f, 0.f);
    for (int i = 0; i < CHUNKS; ++i) {
        const float f = s_f[i];
        float4 ui = *reinterpret_cast<const float4*>(pb + (size_t)i * PSTRIDE + 4 * tid);
        acc.x += f * ui.x; acc.y += f * ui.y; acc.z += f * ui.z; acc.w += f * ui.w;
    }
    acc.x *= invL; acc.y *= invL; acc.z *= invL; acc.w *= invL;
    *reinterpret_cast<float4*>(ubar + (size_t)b * DD + 4 * tid) = acc;
}

// ---------------- K4: ct[b,e] = sum_d ubar[b,d]*W[e,d] + bias[e] (coalesced W rows) ----------------
__global__ __launch_bounds__(256) void k_out(const float* __restrict__ ubar,
                                             const float* __restrict__ W,
                                             const float* __restrict__ bias,
                                             float* __restrict__ out) {
    const int echunk = blockIdx.x;       // 0..31 (32 e each)
    const int bg = blockIdx.y;           // 0..7  (4 b each)
    const int tid = threadIdx.x;
    const int wave = tid >> 6;
    const int lane = tid & 63;
    const int b0 = bg * 4;

    // ubar fragments for 4 batches, lane-pattern 256k+4l
    float4 ur[4][4];
#pragma unroll
    for (int j = 0; j < 4; ++j) {
        const float* ub = ubar + (size_t)(b0 + j) * DD;
#pragma unroll
        for (int k = 0; k < 4; ++k)
            ur[j][k] = *reinterpret_cast<const float4*>(ub + k * 256 + 4 * lane);
    }

    for (int i = 0; i < 8; ++i) {
        const int e = echunk * 32 + wave * 8 + i;
        const float* wr = W + (size_t)e * DD;
        float4 w4[4];
#pragma unroll
        for (int k = 0; k < 4; ++k)
            w4[k] = *reinterpret_cast<const float4*>(wr + k * 256 + 4 * lane);

        float d0 = 0.f, d1 = 0.f, d2 = 0.f, d3 = 0.f;
#pragma unroll
        for (int k = 0; k < 4; ++k) {
            d0 += w4[k].x * ur[0][k].x + w4[k].y * ur[0][k].y + w4[k].z * ur[0][k].z + w4[k].w * ur[0][k].w;
            d1 += w4[k].x * ur[1][k].x + w4[k].y * ur[1][k].y + w4[k].z * ur[1][k].z + w4[k].w * ur[1][k].w;
            d2 += w4[k].x * ur[2][k].x + w4[k].y * ur[2][k].y + w4[k].z * ur[2][k].z + w4[k].w * ur[2][k].w;
            d3 += w4[k].x * ur[3][k].x + w4[k].y * ur[3][k].y + w4[k].z * ur[3][k].z + w4[k].w * ur[3][k].w;
        }
#pragma unroll
        for (int o = 32; o; o >>= 1) {
            d0 += __shfl_xor(d0, o, 64);
            d1 += __shfl_xor(d1, o, 64);
            d2 += __shfl_xor(d2, o, 64);
            d3 += __shfl_xor(d3, o, 64);
        }
        if (lane == 0) {
            const float be = bias[e];
            out[(size_t)(b0 + 0) * DD + e] = d0 + be;
            out[(size_t)(b0 + 1) * DD + e] = d1 + be;
            out[(size_t)(b0 + 2) * DD + e] = d2 + be;
            out[(size_t)(b0 + 3) * DD + e] = d3 + be;
        }
    }
}

extern "C" void kernel_launch(void* const* d_in, const int* in_sizes, int n_in,
                              void* d_out, int out_size, void* d_ws, size_t ws_size,
                              hipStream_t stream) {
    const float* st   = (const float*)d_in[0];   // [B,D]
    const float* hx   = (const float*)d_in[1];   // [B,S,D]
    const float* msk  = (const float*)d_in[2];   // [B,S]
    const float* W    = (const float*)d_in[3];   // [D,D]
    const float* bias = (const float*)d_in[4];   // [D]
    float* out = (float*)d_out;                  // [B,D]

    float* ws = (float*)d_ws;
    float* part_v = ws;                                   // ESPL*B*D = 256K floats
    float* part   = part_v + (size_t)ESPL * BB * DD;      // B*CHUNKS*PSTRIDE
    float* ubar   = part + (size_t)BB * CHUNKS * PSTRIDE; // B*D

    k_v<<<dim3(4, ESPL, VBG), 256, 0, stream>>>(st, W, part_v);
    k_main<<<dim3(CHUNKS, BB), 256, 0, stream>>>(hx, msk, part_v, st, bias, part);
    k_reduce<<<BB, 256, 0, stream>>>(part, ubar);
    k_out<<<dim3(32, 8), 256, 0, stream>>>(ubar, W, bias, out);
}

// Round 3
// 75.941 us; speedup vs baseline: 1.7748x; 1.0760x over previous
//
#include <hip/hip_runtime.h>
#include <math.h>

#define BB 32
#define SS 2048
#define DD 1024
#define CHUNKS 32                        // chunks per batch (k_main grid.x)
#define ROWS_PER_CHUNK (SS / CHUNKS)     // 64
#define NWAVES 4
#define ROWS_PER_WAVE (ROWS_PER_CHUNK / NWAVES)  // 16
#define PSTRIDE (DD + 4)                 // partial stride (16B aligned)

// k_v split
#define ESPL 8
#define EPB (DD / ESPL)                  // 128 e per block
#define VBG 4                            // b-group blocks
#define VBPG (BB / VBG)                  // 8 b per block

// ---------------- K1: part_v[es][b][d] = sum_{e in es-range} st[b,e]*W[e,d] ----------------
__global__ __launch_bounds__(256) void k_v(const float* __restrict__ st,
                                           const float* __restrict__ W,
                                           float* __restrict__ part_v) {
    const int dchunk = blockIdx.x;       // 0..3
    const int es = blockIdx.y;           // 0..7
    const int bg = blockIdx.z;           // 0..3
    const int tid = threadIdx.x;
    const int d = dchunk * 256 + tid;
    const int e0 = es * EPB;
    const int b0 = bg * VBPG;

    __shared__ float st_s[VBPG][EPB];    // 4 KB
    for (int i = tid; i < VBPG * EPB; i += 256)
        st_s[i >> 7][i & 127] = st[(b0 + (i >> 7)) * DD + e0 + (i & 127)];
    __syncthreads();

    float acc[VBPG];
#pragma unroll
    for (int j = 0; j < VBPG; ++j) acc[j] = 0.f;

    for (int e = 0; e < EPB; ++e) {
        const float w = W[(size_t)(e0 + e) * DD + d];
#pragma unroll
        for (int j = 0; j < VBPG; ++j) acc[j] += st_s[j][e] * w;
    }
#pragma unroll
    for (int j = 0; j < VBPG; ++j)
        part_v[((size_t)es * BB + b0 + j) * DD + d] = acc[j];
}

// ---------------- K2: main single pass over hx (online softmax, 2-row groups, dbuf) ----------------
__global__ __launch_bounds__(256) void k_main(const float* __restrict__ hx,
                                              const float* __restrict__ mask,
                                              const float* __restrict__ part_v,
                                              const float* __restrict__ st,
                                              const float* __restrict__ bias,
                                              float* __restrict__ part) {
    const int chunk = blockIdx.x;
    const int b = blockIdx.y;
    const int tid = threadIdx.x;
    const int wave = tid >> 6;
    const int lane = tid & 63;

    // v fragment (lane l owns cols 256k+4l..+3), reduced over the 8 e-splits
    float4 vr[4];
#pragma unroll
    for (int k = 0; k < 4; ++k) vr[k] = make_float4(0.f, 0.f, 0.f, 0.f);
#pragma unroll
    for (int es = 0; es < ESPL; ++es) {
        const float* pv = part_v + ((size_t)es * BB + b) * DD;
#pragma unroll
        for (int k = 0; k < 4; ++k) {
            float4 t = *reinterpret_cast<const float4*>(pv + k * 256 + 4 * lane);
            vr[k].x += t.x; vr[k].y += t.y; vr[k].z += t.z; vr[k].w += t.w;
        }
    }

    // cb = dot(bias, st[b]) computed redundantly per wave (L2-hot reads)
    float cb = 0.f;
    {
        const float* stb = st + b * DD;
#pragma unroll
        for (int k = 0; k < 4; ++k) {
            float4 bv = *reinterpret_cast<const float4*>(bias + k * 256 + 4 * lane);
            float4 sv = *reinterpret_cast<const float4*>(stb + k * 256 + 4 * lane);
            cb += bv.x * sv.x + bv.y * sv.y + bv.z * sv.z + bv.w * sv.w;
        }
#pragma unroll
        for (int o = 32; o; o >>= 1) cb += __shfl_xor(cb, o, 64);
    }

    const int s0 = chunk * ROWS_PER_CHUNK + wave * ROWS_PER_WAVE;
    const float* hxb = hx + (size_t)b * SS * DD + 4 * lane;
    const float* mb = mask + (size_t)b * SS;

    float m = -INFINITY, l = 0.f;
    float4 u[4];
#pragma unroll
    for (int k = 0; k < 4; ++k) u[k] = make_float4(0.f, 0.f, 0.f, 0.f);

    float4 hA[2][4], hB[2][4];

    auto loadrows = [&](float4 (&h)[2][4], int s) {
        const float* r0 = hxb + (size_t)s * DD;
#pragma unroll
        for (int k = 0; k < 4; ++k) {
            h[0][k] = *reinterpret_cast<const float4*>(r0 + k * 256);
            h[1][k] = *reinterpret_cast<const float4*>(r0 + DD + k * 256);
        }
    };

    auto compute = [&](const float4 (&h)[2][4], int s) {
        float d0 = 0.f, d1 = 0.f;
#pragma unroll
        for (int k = 0; k < 4; ++k) {
            d0 += h[0][k].x * vr[k].x + h[0][k].y * vr[k].y + h[0][k].z * vr[k].z + h[0][k].w * vr[k].w;
            d1 += h[1][k].x * vr[k].x + h[1][k].y * vr[k].y + h[1][k].z * vr[k].z + h[1][k].w * vr[k].w;
        }
        // select-mix reduce: 1 mix + 5 butterfly + 1 gather = 7 shfls for 2 rows
        const bool odd = (lane & 1);
        float a = odd ? d1 : d0;
        float t = odd ? d0 : d1;
        a += __shfl_xor(t, 1, 64);
        a += __shfl_xor(a, 2, 64);
        a += __shfl_xor(a, 4, 64);
        a += __shfl_xor(a, 8, 64);
        a += __shfl_xor(a, 16, 64);
        a += __shfl_xor(a, 32, 64);
        const float o = __shfl_xor(a, 1, 64);
        const float dd0 = odd ? o : a;
        const float dd1 = odd ? a : o;

        const float2 mk = *reinterpret_cast<const float2*>(mb + s);
        const float sc0 = (dd0 + cb) * (mk.x + (1.0f - mk.x) * 1e-18f);
        const float sc1 = (dd1 + cb) * (mk.y + (1.0f - mk.y) * 1e-18f);

        const float gm = fmaxf(sc0, sc1);
        if (gm > m) {                        // wave-uniform (post-reduce values)
            const float f = __expf(m - gm);  // 0 on first group (m = -inf)
            l *= f;
#pragma unroll
            for (int k = 0; k < 4; ++k) {
                u[k].x *= f; u[k].y *= f; u[k].z *= f; u[k].w *= f;
            }
            m = gm;
        }
        const float p0 = __expf(sc0 - m);
        const float p1 = __expf(sc1 - m);
        l += p0 + p1;
#pragma unroll
        for (int k = 0; k < 4; ++k) {
            u[k].x += p0 * h[0][k].x + p1 * h[1][k].x;
            u[k].y += p0 * h[0][k].y + p1 * h[1][k].y;
            u[k].z += p0 * h[0][k].z + p1 * h[1][k].z;
            u[k].w += p0 * h[0][k].w + p1 * h[1][k].w;
        }
    };

    // software pipeline over 8 groups of 2 rows, static A/B alternation
    loadrows(hA, s0);
#pragma unroll
    for (int g = 0; g < ROWS_PER_WAVE / 2 - 1; ++g) {
        if (g & 1) { loadrows(hA, s0 + 2 * (g + 1)); compute(hB, s0 + 2 * g); }
        else       { loadrows(hB, s0 + 2 * (g + 1)); compute(hA, s0 + 2 * g); }
    }
    compute(hB, s0 + ROWS_PER_WAVE - 2);   // last group (loaded at g=6 into hB)

    // combine 4 waves in LDS
    __shared__ float s_m[NWAVES], s_l[NWAVES];
    __shared__ float s_u[NWAVES][DD];   // 16 KB
    if (lane == 0) { s_m[wave] = m; s_l[wave] = l; }
#pragma unroll
    for (int k = 0; k < 4; ++k)
        *reinterpret_cast<float4*>(&s_u[wave][k * 256 + 4 * lane]) = u[k];
    __syncthreads();

    const float M = fmaxf(fmaxf(s_m[0], s_m[1]), fmaxf(s_m[2], s_m[3]));
    const float f0 = __expf(s_m[0] - M), f1 = __expf(s_m[1] - M);
    const float f2 = __expf(s_m[2] - M), f3 = __expf(s_m[3] - M);
    const float L = s_l[0] * f0 + s_l[1] * f1 + s_l[2] * f2 + s_l[3] * f3;

    float* pb = part + (size_t)(b * CHUNKS + chunk) * PSTRIDE;
    float4 a0 = *reinterpret_cast<const float4*>(&s_u[0][4 * tid]);
    float4 a1 = *reinterpret_cast<const float4*>(&s_u[1][4 * tid]);
    float4 a2 = *reinterpret_cast<const float4*>(&s_u[2][4 * tid]);
    float4 a3 = *reinterpret_cast<const float4*>(&s_u[3][4 * tid]);
    float4 acc;
    acc.x = a0.x * f0 + a1.x * f1 + a2.x * f2 + a3.x * f3;
    acc.y = a0.y * f0 + a1.y * f1 + a2.y * f2 + a3.y * f3;
    acc.z = a0.z * f0 + a1.z * f1 + a2.z * f2 + a3.z * f3;
    acc.w = a0.w * f0 + a1.w * f1 + a2.w * f2 + a3.w * f3;
    *reinterpret_cast<float4*>(pb + 4 * tid) = acc;
    if (tid == 0) { pb[DD] = M; pb[DD + 1] = L; }
}

// ---------------- K3: combine chunks -> ubar[b,d] = u_total/L ----------------
__global__ __launch_bounds__(256) void k_reduce(const float* __restrict__ part,
                                                float* __restrict__ ubar) {
    const int b = blockIdx.x;
    const int tid = threadIdx.x;
    __shared__ float s_f[CHUNKS];
    __shared__ float s_red[2];
    const float* pb = part + (size_t)b * CHUNKS * PSTRIDE;

    float mi = (tid < CHUNKS) ? pb[tid * PSTRIDE + DD] : -INFINITY;
    float M = mi;
#pragma unroll
    for (int o = 32; o; o >>= 1) M = fmaxf(M, __shfl_xor(M, o, 64));
    if (tid == 0) s_red[0] = M;
    __syncthreads();
    M = s_red[0];

    const float li = (tid < CHUNKS) ? pb[tid * PSTRIDE + DD + 1] : 0.f;
    const float fi = (tid < CHUNKS) ? __expf(mi - M) : 0.f;
    if (tid < CHUNKS) s_f[tid] = fi;
    float Lp = li * fi;
#pragma unroll
    for (int o = 32; o; o >>= 1) Lp += __shfl_xor(Lp, o, 64);
    if (tid == 0) s_red[1] = Lp;
    __syncthreads();
    const float invL = 1.f / s_red[1];

    float4 acc = make_float4(0.f, 0.f, 0.f, 0.f);
    for (int i = 0; i < CHUNKS; ++i) {
        const float f = s_f[i];
        float4 ui = *reinterpret_cast<const float4*>(pb + (size_t)i * PSTRIDE + 4 * tid);
        acc.x += f * ui.x; acc.y += f * ui.y; acc.z += f * ui.z; acc.w += f * ui.w;
    }
    acc.x *= invL; acc.y *= invL; acc.z *= invL; acc.w *= invL;
    *reinterpret_cast<float4*>(ubar + (size_t)b * DD + 4 * tid) = acc;
}

// ---------------- K4: ct[b,e] = sum_d ubar[b,d]*W[e,d] + bias[e] (coalesced W rows) ----------------
__global__ __launch_bounds__(256) void k_out(const float* __restrict__ ubar,
                                             const float* __restrict__ W,
                                             const float* __restrict__ bias,
                                             float* __restrict__ out) {
    const int echunk = blockIdx.x;       // 0..31 (32 e each)
    const int bg = blockIdx.y;           // 0..7  (4 b each)
    const int tid = threadIdx.x;
    const int wave = tid >> 6;
    const int lane = tid & 63;
    const int b0 = bg * 4;

    // ubar fragments for 4 batches, lane-pattern 256k+4l
    float4 ur[4][4];
#pragma unroll
    for (int j = 0; j < 4; ++j) {
        const float* ub = ubar + (size_t)(b0 + j) * DD;
#pragma unroll
        for (int k = 0; k < 4; ++k)
            ur[j][k] = *reinterpret_cast<const float4*>(ub + k * 256 + 4 * lane);
    }

    for (int i = 0; i < 8; ++i) {
        const int e = echunk * 32 + wave * 8 + i;
        const float* wr = W + (size_t)e * DD;
        float4 w4[4];
#pragma unroll
        for (int k = 0; k < 4; ++k)
            w4[k] = *reinterpret_cast<const float4*>(wr + k * 256 + 4 * lane);

        float d0 = 0.f, d1 = 0.f, d2 = 0.f, d3 = 0.f;
#pragma unroll
        for (int k = 0; k < 4; ++k) {
            d0 += w4[k].x * ur[0][k].x + w4[k].y * ur[0][k].y + w4[k].z * ur[0][k].z + w4[k].w * ur[0][k].w;
            d1 += w4[k].x * ur[1][k].x + w4[k].y * ur[1][k].y + w4[k].z * ur[1][k].z + w4[k].w * ur[1][k].w;
            d2 += w4[k].x * ur[2][k].x + w4[k].y * ur[2][k].y + w4[k].z * ur[2][k].z + w4[k].w * ur[2][k].w;
            d3 += w4[k].x * ur[3][k].x + w4[k].y * ur[3][k].y + w4[k].z * ur[3][k].z + w4[k].w * ur[3][k].w;
        }
#pragma unroll
        for (int o = 32; o; o >>= 1) {
            d0 += __shfl_xor(d0, o, 64);
            d1 += __shfl_xor(d1, o, 64);
            d2 += __shfl_xor(d2, o, 64);
            d3 += __shfl_xor(d3, o, 64);
        }
        if (lane == 0) {
            const float be = bias[e];
            out[(size_t)(b0 + 0) * DD + e] = d0 + be;
            out[(size_t)(b0 + 1) * DD + e] = d1 + be;
            out[(size_t)(b0 + 2) * DD + e] = d2 + be;
            out[(size_t)(b0 + 3) * DD + e] = d3 + be;
        }
    }
}

extern "C" void kernel_launch(void* const* d_in, const int* in_sizes, int n_in,
                              void* d_out, int out_size, void* d_ws, size_t ws_size,
                              hipStream_t stream) {
    const float* st   = (const float*)d_in[0];   // [B,D]
    const float* hx   = (const float*)d_in[1];   // [B,S,D]
    const float* msk  = (const float*)d_in[2];   // [B,S]
    const float* W    = (const float*)d_in[3];   // [D,D]
    const float* bias = (const float*)d_in[4];   // [D]
    float* out = (float*)d_out;                  // [B,D]

    float* ws = (float*)d_ws;
    float* part_v = ws;                                   // ESPL*B*D = 256K floats
    float* part   = part_v + (size_t)ESPL * BB * DD;      // B*CHUNKS*PSTRIDE
    float* ubar   = part + (size_t)BB * CHUNKS * PSTRIDE; // B*D

    k_v<<<dim3(4, ESPL, VBG), 256, 0, stream>>>(st, W, part_v);
    k_main<<<dim3(CHUNKS, BB), 256, 0, stream>>>(hx, msk, part_v, st, bias, part);
    k_reduce<<<BB, 256, 0, stream>>>(part, ubar);
    k_out<<<dim3(32, 8), 256, 0, stream>>>(ubar, W, bias, out);
}

// Round 4
// 69.995 us; speedup vs baseline: 1.9255x; 1.0850x over previous
//
#include <hip/hip_runtime.h>
#include <math.h>

#define BB 32
#define SS 2048
#define DD 1024
#define CHUNKS 32                        // chunks per batch (k_main grid.x)
#define ROWS_PER_CHUNK (SS / CHUNKS)     // 64
#define NWAVES 4
#define ROWS_PER_WAVE (ROWS_PER_CHUNK / NWAVES)  // 16
#define PSTRIDE (DD + 4)                 // partial stride (16B aligned)

// k_v split
#define ESPL 8
#define EPB (DD / ESPL)                  // 128 e per block
#define VBG 8                            // b-group blocks
#define VBPG (BB / VBG)                  // 4 b per block

typedef float f32x4 __attribute__((ext_vector_type(4)));

__device__ __forceinline__ f32x4 ldnt4(const float* p) {
    return __builtin_nontemporal_load(reinterpret_cast<const f32x4*>(p));
}
__device__ __forceinline__ f32x4 ld4(const float* p) {
    return *reinterpret_cast<const f32x4*>(p);
}

// ---------------- K1: part_v[es][b][d] = sum_{e in es-range} st[b,e]*W[e,d] ----------------
__global__ __launch_bounds__(256) void k_v(const float* __restrict__ st,
                                           const float* __restrict__ W,
                                           float* __restrict__ part_v) {
    const int dchunk = blockIdx.x;       // 0..3
    const int es = blockIdx.y;           // 0..7
    const int bg = blockIdx.z;           // 0..7
    const int tid = threadIdx.x;
    const int d = dchunk * 256 + tid;
    const int e0 = es * EPB;
    const int b0 = bg * VBPG;

    __shared__ float st_s[VBPG][EPB];    // 2 KB
    for (int i = tid; i < VBPG * EPB; i += 256)
        st_s[i >> 7][i & 127] = st[(b0 + (i >> 7)) * DD + e0 + (i & 127)];
    __syncthreads();

    float acc[VBPG];
#pragma unroll
    for (int j = 0; j < VBPG; ++j) acc[j] = 0.f;

    for (int e = 0; e < EPB; ++e) {
        const float w = W[(size_t)(e0 + e) * DD + d];
#pragma unroll
        for (int j = 0; j < VBPG; ++j) acc[j] += st_s[j][e] * w;
    }
#pragma unroll
    for (int j = 0; j < VBPG; ++j)
        part_v[((size_t)es * BB + b0 + j) * DD + d] = acc[j];
}

// ---------------- K2: main single pass over hx (online softmax, 2-row groups, dbuf) ----------------
__global__ __launch_bounds__(256, 4) void k_main(const float* __restrict__ hx,
                                                 const float* __restrict__ mask,
                                                 const float* __restrict__ part_v,
                                                 const float* __restrict__ st,
                                                 const float* __restrict__ bias,
                                                 float* __restrict__ part) {
    const int chunk = blockIdx.x;
    const int b = blockIdx.y;
    const int tid = threadIdx.x;
    const int wave = tid >> 6;
    const int lane = tid & 63;

    // v fragment (lane l owns cols 256k+4l..+3), reduced over the 8 e-splits
    f32x4 vr[4];
#pragma unroll
    for (int k = 0; k < 4; ++k) vr[k] = (f32x4)(0.f);
#pragma unroll
    for (int es = 0; es < ESPL; ++es) {
        const float* pv = part_v + ((size_t)es * BB + b) * DD + 4 * lane;
#pragma unroll
        for (int k = 0; k < 4; ++k) vr[k] += ld4(pv + k * 256);
    }

    // cb = dot(bias, st[b]) computed redundantly per wave (L2-hot reads)
    float cb = 0.f;
    {
        const float* stb = st + b * DD + 4 * lane;
        const float* bb = bias + 4 * lane;
#pragma unroll
        for (int k = 0; k < 4; ++k) {
            f32x4 bv = ld4(bb + k * 256);
            f32x4 sv = ld4(stb + k * 256);
            cb += bv.x * sv.x + bv.y * sv.y + bv.z * sv.z + bv.w * sv.w;
        }
#pragma unroll
        for (int o = 32; o; o >>= 1) cb += __shfl_xor(cb, o, 64);
    }

    const int s0 = chunk * ROWS_PER_CHUNK + wave * ROWS_PER_WAVE;
    const float* hxb = hx + (size_t)b * SS * DD + 4 * lane;
    const float* mb = mask + (size_t)b * SS;

    float m = -INFINITY, l = 0.f;
    f32x4 u[4];
#pragma unroll
    for (int k = 0; k < 4; ++k) u[k] = (f32x4)(0.f);

    f32x4 hA[2][4], hB[2][4];

    auto loadrows = [&](f32x4 (&h)[2][4], int s) {
        const float* r0 = hxb + (size_t)s * DD;
#pragma unroll
        for (int k = 0; k < 4; ++k) {
            h[0][k] = ldnt4(r0 + k * 256);
            h[1][k] = ldnt4(r0 + DD + k * 256);
        }
    };

    auto compute = [&](const f32x4 (&h)[2][4], int s) {
        float d0 = 0.f, d1 = 0.f;
#pragma unroll
        for (int k = 0; k < 4; ++k) {
            d0 += h[0][k].x * vr[k].x + h[0][k].y * vr[k].y + h[0][k].z * vr[k].z + h[0][k].w * vr[k].w;
            d1 += h[1][k].x * vr[k].x + h[1][k].y * vr[k].y + h[1][k].z * vr[k].z + h[1][k].w * vr[k].w;
        }
        // select-mix reduce: 1 mix + 5 butterfly + 1 gather = 7 shfls for 2 rows
        const bool odd = (lane & 1);
        float a = odd ? d1 : d0;
        float t = odd ? d0 : d1;
        a += __shfl_xor(t, 1, 64);
        a += __shfl_xor(a, 2, 64);
        a += __shfl_xor(a, 4, 64);
        a += __shfl_xor(a, 8, 64);
        a += __shfl_xor(a, 16, 64);
        a += __shfl_xor(a, 32, 64);
        const float o = __shfl_xor(a, 1, 64);
        const float dd0 = odd ? o : a;
        const float dd1 = odd ? a : o;

        const float2 mk = *reinterpret_cast<const float2*>(mb + s);
        const float sc0 = (dd0 + cb) * (mk.x + (1.0f - mk.x) * 1e-18f);
        const float sc1 = (dd1 + cb) * (mk.y + (1.0f - mk.y) * 1e-18f);

        const float gm = fmaxf(sc0, sc1);
        if (gm > m) {                        // wave-uniform (post-reduce values)
            const float f = __expf(m - gm);  // 0 on first group (m = -inf)
            l *= f;
#pragma unroll
            for (int k = 0; k < 4; ++k) u[k] *= f;
            m = gm;
        }
        const float p0 = __expf(sc0 - m);
        const float p1 = __expf(sc1 - m);
        l += p0 + p1;
#pragma unroll
        for (int k = 0; k < 4; ++k) u[k] += p0 * h[0][k] + p1 * h[1][k];
    };

    // software pipeline over 8 groups of 2 rows, static A/B alternation
    loadrows(hA, s0);
#pragma unroll
    for (int g = 0; g < ROWS_PER_WAVE / 2 - 1; ++g) {
        if (g & 1) { loadrows(hA, s0 + 2 * (g + 1)); compute(hB, s0 + 2 * g); }
        else       { loadrows(hB, s0 + 2 * (g + 1)); compute(hA, s0 + 2 * g); }
    }
    compute(hB, s0 + ROWS_PER_WAVE - 2);   // last group (loaded at g=6 into hB)

    // combine 4 waves in LDS
    __shared__ float s_m[NWAVES], s_l[NWAVES];
    __shared__ float s_u[NWAVES][DD];   // 16 KB
    if (lane == 0) { s_m[wave] = m; s_l[wave] = l; }
#pragma unroll
    for (int k = 0; k < 4; ++k)
        *reinterpret_cast<f32x4*>(&s_u[wave][k * 256 + 4 * lane]) = u[k];
    __syncthreads();

    const float M = fmaxf(fmaxf(s_m[0], s_m[1]), fmaxf(s_m[2], s_m[3]));
    const float f0 = __expf(s_m[0] - M), f1 = __expf(s_m[1] - M);
    const float f2 = __expf(s_m[2] - M), f3 = __expf(s_m[3] - M);
    const float L = s_l[0] * f0 + s_l[1] * f1 + s_l[2] * f2 + s_l[3] * f3;

    float* pb = part + (size_t)(b * CHUNKS + chunk) * PSTRIDE;
    f32x4 a0 = ld4(&s_u[0][4 * tid]);
    f32x4 a1 = ld4(&s_u[1][4 * tid]);
    f32x4 a2 = ld4(&s_u[2][4 * tid]);
    f32x4 a3 = ld4(&s_u[3][4 * tid]);
    f32x4 acc = a0 * f0 + a1 * f1 + a2 * f2 + a3 * f3;
    *reinterpret_cast<f32x4*>(pb + 4 * tid) = acc;
    if (tid == 0) { pb[DD] = M; pb[DD + 1] = L; }
}

// ---------------- K3: combine chunks -> ubar[b,d] = u_total/L ----------------
__global__ __launch_bounds__(256) void k_reduce(const float* __restrict__ part,
                                                float* __restrict__ ubar) {
    const int b = blockIdx.x;
    const int tid = threadIdx.x;
    __shared__ float s_f[CHUNKS];
    __shared__ float s_red[2];
    const float* pb = part + (size_t)b * CHUNKS * PSTRIDE;

    float mi = (tid < CHUNKS) ? pb[tid * PSTRIDE + DD] : -INFINITY;
    float M = mi;
#pragma unroll
    for (int o = 32; o; o >>= 1) M = fmaxf(M, __shfl_xor(M, o, 64));
    if (tid == 0) s_red[0] = M;
    __syncthreads();
    M = s_red[0];

    const float li = (tid < CHUNKS) ? pb[tid * PSTRIDE + DD + 1] : 0.f;
    const float fi = (tid < CHUNKS) ? __expf(mi - M) : 0.f;
    if (tid < CHUNKS) s_f[tid] = fi;
    float Lp = li * fi;
#pragma unroll
    for (int o = 32; o; o >>= 1) Lp += __shfl_xor(Lp, o, 64);
    if (tid == 0) s_red[1] = Lp;
    __syncthreads();
    const float invL = 1.f / s_red[1];

    f32x4 acc = (f32x4)(0.f);
    for (int i = 0; i < CHUNKS; ++i) {
        const float f = s_f[i];
        f32x4 ui = ld4(pb + (size_t)i * PSTRIDE + 4 * tid);
        acc += f * ui;
    }
    acc *= invL;
    *reinterpret_cast<f32x4*>(ubar + (size_t)b * DD + 4 * tid) = acc;
}

// ---------------- K4: ct[b,e] = sum_d ubar[b,d]*W[e,d] + bias[e] (coalesced W rows) ----------------
__global__ __launch_bounds__(256) void k_out(const float* __restrict__ ubar,
                                             const float* __restrict__ W,
                                             const float* __restrict__ bias,
                                             float* __restrict__ out) {
    const int echunk = blockIdx.x;       // 0..63 (16 e each)
    const int bg = blockIdx.y;           // 0..7  (4 b each)
    const int tid = threadIdx.x;
    const int wave = tid >> 6;
    const int lane = tid & 63;
    const int b0 = bg * 4;

    // ubar fragments for 4 batches, lane-pattern 256k+4l
    f32x4 ur[4][4];
#pragma unroll
    for (int j = 0; j < 4; ++j) {
        const float* ub = ubar + (size_t)(b0 + j) * DD + 4 * lane;
#pragma unroll
        for (int k = 0; k < 4; ++k) ur[j][k] = ld4(ub + k * 256);
    }

    for (int i = 0; i < 4; ++i) {
        const int e = echunk * 16 + wave * 4 + i;
        const float* wr = W + (size_t)e * DD + 4 * lane;
        f32x4 w4[4];
#pragma unroll
        for (int k = 0; k < 4; ++k) w4[k] = ld4(wr + k * 256);

        float d0 = 0.f, d1 = 0.f, d2 = 0.f, d3 = 0.f;
#pragma unroll
        for (int k = 0; k < 4; ++k) {
            d0 += w4[k].x * ur[0][k].x + w4[k].y * ur[0][k].y + w4[k].z * ur[0][k].z + w4[k].w * ur[0][k].w;
            d1 += w4[k].x * ur[1][k].x + w4[k].y * ur[1][k].y + w4[k].z * ur[1][k].z + w4[k].w * ur[1][k].w;
            d2 += w4[k].x * ur[2][k].x + w4[k].y * ur[2][k].y + w4[k].z * ur[2][k].z + w4[k].w * ur[2][k].w;
            d3 += w4[k].x * ur[3][k].x + w4[k].y * ur[3][k].y + w4[k].z * ur[3][k].z + w4[k].w * ur[3][k].w;
        }
#pragma unroll
        for (int o = 32; o; o >>= 1) {
            d0 += __shfl_xor(d0, o, 64);
            d1 += __shfl_xor(d1, o, 64);
            d2 += __shfl_xor(d2, o, 64);
            d3 += __shfl_xor(d3, o, 64);
        }
        if (lane == 0) {
            const float be = bias[e];
            out[(size_t)(b0 + 0) * DD + e] = d0 + be;
            out[(size_t)(b0 + 1) * DD + e] = d1 + be;
            out[(size_t)(b0 + 2) * DD + e] = d2 + be;
            out[(size_t)(b0 + 3) * DD + e] = d3 + be;
        }
    }
}

extern "C" void kernel_launch(void* const* d_in, const int* in_sizes, int n_in,
                              void* d_out, int out_size, void* d_ws, size_t ws_size,
                              hipStream_t stream) {
    const float* st   = (const float*)d_in[0];   // [B,D]
    const float* hx   = (const float*)d_in[1];   // [B,S,D]
    const float* msk  = (const float*)d_in[2];   // [B,S]
    const float* W    = (const float*)d_in[3];   // [D,D]
    const float* bias = (const float*)d_in[4];   // [D]
    float* out = (float*)d_out;                  // [B,D]

    float* ws = (float*)d_ws;
    float* part_v = ws;                                   // ESPL*B*D = 256K floats
    float* part   = part_v + (size_t)ESPL * BB * DD;      // B*CHUNKS*PSTRIDE
    float* ubar   = part + (size_t)BB * CHUNKS * PSTRIDE; // B*D

    k_v<<<dim3(4, ESPL, VBG), 256, 0, stream>>>(st, W, part_v);
    k_main<<<dim3(CHUNKS, BB), 256, 0, stream>>>(hx, msk, part_v, st, bias, part);
    k_reduce<<<BB, 256, 0, stream>>>(part, ubar);
    k_out<<<dim3(64, 8), 256, 0, stream>>>(ubar, W, bias, out);
}